// Round 5
// baseline (676.674 us; speedup 1.0000x reference)
//
#include <hip/hip_runtime.h>
#include <hip/hip_bf16.h>
#include <hip/hip_cooperative_groups.h>

namespace cg = cooperative_groups;

#define BN_EPS 1e-5f
#define NBMAX 512      // max buckets (N/256)
#define CHUNK 4096     // edges per binning block
#define CAP   5120     // fixed per-bucket capacity (mean 4096 + 16 sigma)
#define PCAP  7168     // padded per-bucket adj capacity (CAP + 256*7 = 6912 <= 7168, mult of 8)

typedef __hip_bfloat16 bf16;
typedef __attribute__((ext_vector_type(8))) short short8;
typedef __attribute__((ext_vector_type(4))) float f32x4;

__device__ __forceinline__ float b2f(bf16 v) { return __bfloat162float(v); }
__device__ __forceinline__ bf16 f2b(float v) { return __float2bfloat16(v); }
__device__ __forceinline__ float bl(unsigned u) { return __uint_as_float(u << 16); }
__device__ __forceinline__ float bh(unsigned u) { return __uint_as_float(u & 0xffff0000u); }
__device__ __forceinline__ unsigned pack2(float x, float y) {
    union { bf16 b[2]; unsigned u; } p;
    p.b[0] = f2b(x); p.b[1] = f2b(y);
    return p.u;
}
__device__ __forceinline__ float bs2f(short s) {
    return __uint_as_float(((unsigned)(unsigned short)s) << 16);
}
__device__ __forceinline__ short f2bs(float v) {
    bf16 b = f2b(v);
    return *reinterpret_cast<short*>(&b);
}

// ============ init bcur (fixed-stride bases) + cast x -> bf16 (pad rows = 0) ====
__global__ __launch_bounds__(256) void initcast_k(
    const float* __restrict__ in, bf16* __restrict__ xb, bf16* __restrict__ hb,
    int n4, int total4, int* __restrict__ bcur, int NB)
{
    if (blockIdx.x == 0) {
        for (int i = threadIdx.x; i < NB; i += 256) bcur[i] = i * CAP;
        if (threadIdx.x < 16) {   // zero pad row N of hb
            ushort4 z; z.x = 0; z.y = 0; z.z = 0; z.w = 0;
            ((ushort4*)hb)[(size_t)n4 + threadIdx.x] = z;
        }
    }
    int i = blockIdx.x * 256 + threadIdx.x;
    if (i >= total4) return;
    if (i < n4) {
        float4 v = ((const float4*)in)[i];
        union { ushort4 u; bf16 b[4]; } p;
        p.b[0] = f2b(v.x); p.b[1] = f2b(v.y); p.b[2] = f2b(v.z); p.b[3] = f2b(v.w);
        ((ushort4*)xb)[i] = p.u;
    } else {
        ushort4 z; z.x = 0; z.y = 0; z.z = 0; z.w = 0;
        ((ushort4*)xb)[i] = z;   // zero pad row N of xb
    }
}

// ============ binscatter: group edges by bucket in LDS, write coalesced runs ====
__global__ __launch_bounds__(256) void binscatter_k(
    const int* __restrict__ src, const int* __restrict__ dst,
    int* __restrict__ bcur, int* __restrict__ tmp, int E, int NB)
{
    __shared__ int hist[NBMAX];
    __shared__ int loff[NBMAX];
    __shared__ int gb[NBMAX];
    __shared__ int lcur[NBMAX];
    __shared__ int staged[CHUNK];
    __shared__ unsigned short sb[CHUNK];
    __shared__ int ssc[256];
    const int t = threadIdx.x;
    for (int i = t; i < NB; i += 256) { hist[i] = 0; lcur[i] = 0; }
    __syncthreads();
    const int base = blockIdx.x * CHUNK;
    const int lim = min(CHUNK, E - base);
    int myb[16], myw[16];
    int cnt = 0;
    for (int i = t; i < lim; i += 256) {
        int d = dst[base + i];
        int s_ = src[base + i];
        int b = d >> 8;
        myb[cnt] = b;
        myw[cnt] = (s_ << 8) | (d & 255);
        cnt++;
        atomicAdd(&hist[b], 1);
    }
    __syncthreads();
    int v0 = (2 * t     < NB) ? hist[2 * t]     : 0;
    int v1 = (2 * t + 1 < NB) ? hist[2 * t + 1] : 0;
    ssc[t] = v0 + v1;
    __syncthreads();
    for (int off = 1; off < 256; off <<= 1) {
        int a = (t >= off) ? ssc[t - off] : 0;
        __syncthreads();
        ssc[t] += a;
        __syncthreads();
    }
    int excl = ssc[t] - (v0 + v1);
    if (2 * t < NB)     loff[2 * t] = excl;
    if (2 * t + 1 < NB) loff[2 * t + 1] = excl + v0;
    __syncthreads();
    for (int b = t; b < NB; b += 256)
        if (hist[b] > 0) gb[b] = atomicAdd(&bcur[b], hist[b]);
    for (int i = 0; i < cnt; i++) {
        int b = myb[i];
        int p = loff[b] + atomicAdd(&lcur[b], 1);
        staged[p] = myw[i];
        sb[p] = (unsigned short)b;
    }
    __syncthreads();
    for (int i = t; i < lim; i += 256) {
        int b = sb[i];
        tmp[gb[b] + (i - loff[b])] = staged[i];
    }
}

// ============ csr: per bucket counting sort -> 8-padded rows (pad idx = N) ======
__global__ __launch_bounds__(256) void csr_k(
    const int* __restrict__ bcur, const int* __restrict__ tmp,
    int* __restrict__ rowptr, int* __restrict__ rowend,
    int* __restrict__ adj, int N)
{
    __shared__ int hist[256], pfx[256], cur[256], ssc[256];
    __shared__ int sadj[PCAP];
    const int b = blockIdx.x, t = threadIdx.x;
    const int lo = b * CAP;          // tmp base (unpadded)
    const int plo = b * PCAP;        // adj base (padded)
    const int cnt = min(bcur[b] - lo, CAP);
    hist[t] = 0; cur[t] = 0;
    __syncthreads();
    for (int i = t; i < cnt; i += 256)
        atomicAdd(&hist[tmp[lo + i] & 255], 1);
    __syncthreads();
    const int v = hist[t];
    const int pv = (v + 7) & ~7;     // pad each row to multiple of 8
    ssc[t] = pv;
    __syncthreads();
    for (int off = 1; off < 256; off <<= 1) {
        int a = (t >= off) ? ssc[t - off] : 0;
        __syncthreads();
        ssc[t] += a;
        __syncthreads();
    }
    const int myp = ssc[t] - pv;
    pfx[t] = myp;
    const int node = b * 256 + t;
    if (node < N) {
        rowptr[node] = plo + myp;
        rowend[node] = plo + myp + pv;
    }
    __syncthreads();
    const int pcnt = ssc[255];       // <= CAP + 256*7 = 6912 <= PCAP always
    for (int i = t; i < cnt; i += 256) {
        int w = tmp[lo + i];
        int d = w & 255;
        int p = pfx[d] + atomicAdd(&cur[d], 1);
        sadj[p] = w >> 8;
    }
    __syncthreads();
    for (int i = v; i < pv; i++) sadj[myp + i] = N;   // pad -> zero row
    __syncthreads();
    for (int i = t; i < pcnt; i += 256) adj[plo + i] = sadj[i];
}

// ========== aggregation: z[n] = h[n] + sum_m h[m]; rows 8-padded, branch-free ==
// 16 lanes per node, dwordx2 loads: one gather instr = full 128B row per group.
__global__ __launch_bounds__(256, 4) void aggregate_k(
    const bf16* __restrict__ h, const int* __restrict__ rowptr,
    const int* __restrict__ rowend, const int* __restrict__ adj,
    bf16* __restrict__ z, int N)
{
    const int lane16 = threadIdx.x & 15;
    const int n = blockIdx.x * 16 + (threadIdx.x >> 4);
    if (n >= N) return;
    const char* hb_ = (const char*)h;   // row stride 128B
    const int b = rowptr[n], e = rowend[n];

    uint2 u = *(const uint2*)(hb_ + ((size_t)n << 7) + (lane16 << 3));
    float s0 = bl(u.x), s1 = bh(u.x), s2 = bl(u.y), s3 = bh(u.y);

    int m[8];
    if (b < e) {
        #pragma unroll
        for (int k = 0; k < 8; k++) m[k] = adj[b + k];
    }
    for (int i = b; i < e; ) {
        uint2 w[8];
        #pragma unroll
        for (int k = 0; k < 8; k++)
            w[k] = *(const uint2*)(hb_ + (((size_t)(unsigned)m[k]) << 7) + (lane16 << 3));
        const int inext = i + 8;
        if (inext < e) {
            #pragma unroll
            for (int k = 0; k < 8; k++) m[k] = adj[inext + k];
        }
        #pragma unroll
        for (int k = 0; k < 8; k++) {
            s0 += bl(w[k].x); s1 += bh(w[k].x);
            s2 += bl(w[k].y); s3 += bh(w[k].y);
        }
        i = inext;
    }
    uint2 o;
    o.x = pack2(s0, s1);
    o.y = pack2(s2, s3);
    *(uint2*)((char*)z + ((size_t)n << 7) + (lane16 << 3)) = o;
}

// ---------------- fused MLP (cooperative): whole GIN-conv MLP in one kernel ------
// y = relu(bn1(z@W1+b1; stats over N)) @ W2 + b2, stats of y; L0 additionally
// writes h = relu(bn2(y)).  Pass A computes t-stats only (no store); after a
// grid sync every block reduces pstat redundantly; pass B recomputes t (cheap),
// applies act in f32, stages act(t) in a 128x68 LDS tile per chunk for gemm2.
// grid = 256 blocks (1/CU), each owns RPB contiguous rows.
template<int L>
__global__ __launch_bounds__(256) void mlp_k(
    const bf16* __restrict__ A, bf16* __restrict__ Y, bf16* __restrict__ H,
    const float* __restrict__ W1, const float* __restrict__ B1,
    const float* __restrict__ G1, const float* __restrict__ BE1,
    const float* __restrict__ W2, const float* __restrict__ B2,
    const float* __restrict__ G2, const float* __restrict__ BE2,
    float* __restrict__ pstat, float* __restrict__ pstat2,
    float* __restrict__ scB, float* __restrict__ shB,
    int N, int RPB, float invN, int GRID)
{
    cg::grid_group grid = cg::this_grid();
    __shared__ bf16 sWt1[64][72], sWt2[64][72];   // transposed weights (n-major)
    __shared__ bf16 sT[128][68];                  // per-chunk staging tile
    __shared__ float sredS[64][17], sredQ[64][17];
    __shared__ float sSc[64], sSh[64], sB1[64], sB2[64];
    const int tid = threadIdx.x;

    if (tid < 64) { sB1[tid] = B1[tid]; sB2[tid] = B2[tid]; }
    for (int i = tid; i < 4096; i += 256) {
        int k = i >> 6, n = i & 63;
        sWt1[n][k] = f2b(W1[i]);
        sWt2[n][k] = f2b(W2[i]);
    }
    __syncthreads();

    const int blk = blockIdx.x;
    const int r0 = blk * RPB;
    const int rEnd = min(N, r0 + RPB);
    const int CH = (RPB + 127) >> 7;
    const int wave = tid >> 6, lane = tid & 63;
    const int quad = lane >> 4, l16 = lane & 15;

    // ---- pass A: stats of t = A@W1 + b1 (no store) ----
    float psS[4], psQ[4];
    #pragma unroll
    for (int t = 0; t < 4; t++) { psS[t] = 0.f; psQ[t] = 0.f; }

    for (int c = 0; c < CH; c++) {
        const int rbase = r0 + c * 128 + wave * 32;
        short8 a[2][2];
        #pragma unroll
        for (int rt = 0; rt < 2; rt++) {
            int r = rbase + rt * 16 + l16;
            int rr = min(r, rEnd - 1);
            const bf16* arow = A + (size_t)rr * 64;
            a[rt][0] = *(const short8*)(arow + quad * 8);
            a[rt][1] = *(const short8*)(arow + 32 + quad * 8);
        }
        #pragma unroll
        for (int t = 0; t < 4; t++) {
            const int n = t * 16 + l16;
            short8 b0 = *(const short8*)&sWt1[n][quad * 8];
            short8 b1 = *(const short8*)&sWt1[n][32 + quad * 8];
            const float bn_ = sB1[n];
            #pragma unroll
            for (int rt = 0; rt < 2; rt++) {
                f32x4 acc = {0.f, 0.f, 0.f, 0.f};
                acc = __builtin_amdgcn_mfma_f32_16x16x32_bf16(a[rt][0], b0, acc, 0, 0, 0);
                acc = __builtin_amdgcn_mfma_f32_16x16x32_bf16(a[rt][1], b1, acc, 0, 0, 0);
                #pragma unroll
                for (int reg = 0; reg < 4; reg++) {
                    const int grow = rbase + rt * 16 + quad * 4 + reg;
                    float v = acc[reg] + bn_;
                    if (grow < rEnd) { psS[t] += v; psQ[t] = fmaf(v, v, psQ[t]); }
                }
            }
        }
    }
    #pragma unroll
    for (int t = 0; t < 4; t++) {
        sredS[t * 16 + l16][wave * 4 + quad] = psS[t];
        sredQ[t * 16 + l16][wave * 4 + quad] = psQ[t];
    }
    __syncthreads();
    if (tid < 128) {
        const int c = tid & 63;
        const float* p = (tid < 64) ? &sredS[c][0] : &sredQ[c][0];
        float s = 0.f;
        #pragma unroll
        for (int i = 0; i < 16; i++) s += p[i];
        pstat[(size_t)blk * 128 + (tid < 64 ? c : 64 + c)] = s;
    }
    grid.sync();

    // every block redundantly reduces pstat -> sc1/sh1
    if (tid < 64) {
        float S = 0.f, Q = 0.f;
        for (int b = 0; b < GRID; b++) {
            S += pstat[(size_t)b * 128 + tid];
            Q += pstat[(size_t)b * 128 + 64 + tid];
        }
        float m = S * invN;
        float var = Q * invN - m * m;
        float s = G1[tid] * rsqrtf(var + BN_EPS);
        sSc[tid] = s;
        sSh[tid] = BE1[tid] - m * s;
    }
    __syncthreads();

    // ---- pass B: recompute t, act1 (f32), gemm2 via LDS tile, y + stats ----
    #pragma unroll
    for (int t = 0; t < 4; t++) { psS[t] = 0.f; psQ[t] = 0.f; }

    for (int c = 0; c < CH; c++) {
        const int rbase = r0 + c * 128 + wave * 32;
        short8 a[2][2];
        #pragma unroll
        for (int rt = 0; rt < 2; rt++) {
            int r = rbase + rt * 16 + l16;
            int rr = min(r, rEnd - 1);
            const bf16* arow = A + (size_t)rr * 64;
            a[rt][0] = *(const short8*)(arow + quad * 8);
            a[rt][1] = *(const short8*)(arow + 32 + quad * 8);
        }
        #pragma unroll
        for (int t = 0; t < 4; t++) {
            const int n = t * 16 + l16;
            short8 b0 = *(const short8*)&sWt1[n][quad * 8];
            short8 b1 = *(const short8*)&sWt1[n][32 + quad * 8];
            const float bn_ = sB1[n];
            const float sc = sSc[n], sh = sSh[n];
            #pragma unroll
            for (int rt = 0; rt < 2; rt++) {
                f32x4 acc = {0.f, 0.f, 0.f, 0.f};
                acc = __builtin_amdgcn_mfma_f32_16x16x32_bf16(a[rt][0], b0, acc, 0, 0, 0);
                acc = __builtin_amdgcn_mfma_f32_16x16x32_bf16(a[rt][1], b1, acc, 0, 0, 0);
                #pragma unroll
                for (int reg = 0; reg < 4; reg++) {
                    const int lr = wave * 32 + rt * 16 + quad * 4 + reg;
                    float v = acc[reg] + bn_;
                    sT[lr][n] = f2b(fmaxf(fmaf(v, sc, sh), 0.f));
                }
            }
        }
        // gemm2: each wave reads a2 from its OWN 32-row band (no barrier needed)
        short8 a2[2][2];
        #pragma unroll
        for (int rt = 0; rt < 2; rt++) {
            const int lr = wave * 32 + rt * 16 + l16;
            a2[rt][0] = *(const short8*)&sT[lr][quad * 8];
            a2[rt][1] = *(const short8*)&sT[lr][32 + quad * 8];
        }
        #pragma unroll
        for (int t = 0; t < 4; t++) {
            const int n = t * 16 + l16;
            short8 b0 = *(const short8*)&sWt2[n][quad * 8];
            short8 b1 = *(const short8*)&sWt2[n][32 + quad * 8];
            const float bn_ = sB2[n];
            #pragma unroll
            for (int rt = 0; rt < 2; rt++) {
                f32x4 acc = {0.f, 0.f, 0.f, 0.f};
                acc = __builtin_amdgcn_mfma_f32_16x16x32_bf16(a2[rt][0], b0, acc, 0, 0, 0);
                acc = __builtin_amdgcn_mfma_f32_16x16x32_bf16(a2[rt][1], b1, acc, 0, 0, 0);
                #pragma unroll
                for (int reg = 0; reg < 4; reg++) {
                    const int lr = wave * 32 + rt * 16 + quad * 4 + reg;
                    const int grow = rbase + rt * 16 + quad * 4 + reg;
                    float v = acc[reg] + bn_;
                    sT[lr][n] = f2b(v);       // own band only (a2 already in regs)
                    if (grow < rEnd) { psS[t] += v; psQ[t] = fmaf(v, v, psQ[t]); }
                }
            }
        }
        __syncthreads();
        // coalesced y writeout for this chunk
        const int gbase = r0 + c * 128;
        #pragma unroll
        for (int it = 0; it < 8; it++) {
            int idx = it * 256 + tid;
            int r = idx >> 4, c4 = idx & 15;
            if (gbase + r < rEnd) {
                ushort4 v = *(const ushort4*)&sT[r][c4 * 4];
                *(ushort4*)(Y + (size_t)(gbase + r) * 64 + c4 * 4) = v;
            }
        }
        __syncthreads();
    }
    #pragma unroll
    for (int t = 0; t < 4; t++) {
        sredS[t * 16 + l16][wave * 4 + quad] = psS[t];
        sredQ[t * 16 + l16][wave * 4 + quad] = psQ[t];
    }
    __syncthreads();
    if (tid < 128) {
        const int c = tid & 63;
        const float* p = (tid < 64) ? &sredS[c][0] : &sredQ[c][0];
        float s = 0.f;
        #pragma unroll
        for (int i = 0; i < 16; i++) s += p[i];
        pstat2[(size_t)blk * 128 + (tid < 64 ? c : 64 + c)] = s;
    }
    grid.sync();

    if (L == 0) {
        // fused outer bn+relu: h = relu(y*scA+shA), own rows (L2-hot)
        if (tid < 64) {
            float S = 0.f, Q = 0.f;
            for (int b = 0; b < GRID; b++) {
                S += pstat2[(size_t)b * 128 + tid];
                Q += pstat2[(size_t)b * 128 + 64 + tid];
            }
            float m = S * invN;
            float var = Q * invN - m * m;
            float s = G2[tid] * rsqrtf(var + BN_EPS);
            sSc[tid] = s;
            sSh[tid] = BE2[tid] - m * s;
        }
        __syncthreads();
        for (int idx = r0 * 8 + tid; idx < rEnd * 8; idx += 256) {
            const int f0 = (idx & 7) * 8;
            short8 v = *(const short8*)(Y + (size_t)idx * 8);
            #pragma unroll
            for (int j = 0; j < 8; j++)
                v[j] = f2bs(fmaxf(fmaf(bs2f(v[j]), sSc[f0 + j], sSh[f0 + j]), 0.f));
            *(short8*)(H + (size_t)idx * 8) = v;
        }
    } else {
        // emit scB/shB for the pool readout
        if (blk == 0 && tid < 64) {
            float S = 0.f, Q = 0.f;
            for (int b = 0; b < GRID; b++) {
                S += pstat2[(size_t)b * 128 + tid];
                Q += pstat2[(size_t)b * 128 + 64 + tid];
            }
            float m = S * invN;
            float var = Q * invN - m * m;
            float s = G2[tid] * rsqrtf(var + BN_EPS);
            scB[tid] = s;
            shB[tid] = BE2[tid] - m * s;
        }
    }
}

// ---------------- pooled readout; h1 pre-materialized, h2 affine on the fly ------
__global__ __launch_bounds__(256) void pool_readout_k(
    const bf16* __restrict__ xb, const bf16* __restrict__ h1,
    const bf16* __restrict__ y1, const int* __restrict__ batch,
    const float* __restrict__ scB, const float* __restrict__ shB,
    const float* __restrict__ w0, const float* __restrict__ b0,
    const float* __restrict__ w1, const float* __restrict__ b1,
    const float* __restrict__ w2, const float* __restrict__ b2,
    float* __restrict__ out, int Nn)
{
    __shared__ float sB2[2][64];
    __shared__ float p[3][16][64];
    __shared__ float q[3][64];
    const int tid = threadIdx.x;
    if (tid < 64) { sB2[0][tid] = scB[tid]; sB2[1][tid] = shB[tid]; }
    __syncthreads();

    const int g = blockIdx.x;
    int lo = 0, hi = Nn;
    while (lo < hi) { int mid = (lo + hi) >> 1; if (batch[mid] < g) lo = mid + 1; else hi = mid; }
    const int start = lo;
    hi = Nn;
    while (lo < hi) { int mid = (lo + hi) >> 1; if (batch[mid] <= g) lo = mid + 1; else hi = mid; }
    const int end = lo;

    const int l16 = tid & 15, grp = tid >> 4;
    const int f0 = l16 * 4;
    const float scB0 = sB2[0][f0],      shB0 = sB2[1][f0];
    const float scB1 = sB2[0][f0 + 1],  shB1 = sB2[1][f0 + 1];
    const float scB2_ = sB2[0][f0 + 2], shB2_ = sB2[1][f0 + 2];
    const float scB3 = sB2[0][f0 + 3],  shB3 = sB2[1][f0 + 3];

    float a0 = 0.f, a1 = 0.f, a2 = 0.f, a3 = 0.f;
    float h0 = 0.f, h1s = 0.f, h2 = 0.f, h3 = 0.f;
    float c0 = 0.f, c1 = 0.f, c2 = 0.f, c3 = 0.f;
    for (int i = start + grp; i < end; i += 16) {
        const size_t ro = (size_t)i * 16 + l16;
        uint2 ux = ((const uint2*)xb)[ro];
        uint2 u0 = ((const uint2*)h1)[ro];
        uint2 u1 = ((const uint2*)y1)[ro];
        a0 += bl(ux.x); a1 += bh(ux.x); a2 += bl(ux.y); a3 += bh(ux.y);
        h0 += bl(u0.x); h1s += bh(u0.x); h2 += bl(u0.y); h3 += bh(u0.y);
        c0 += fmaxf(fmaf(bl(u1.x), scB0, shB0), 0.f);
        c1 += fmaxf(fmaf(bh(u1.x), scB1, shB1), 0.f);
        c2 += fmaxf(fmaf(bl(u1.y), scB2_, shB2_), 0.f);
        c3 += fmaxf(fmaf(bh(u1.y), scB3, shB3), 0.f);
    }
    p[0][grp][f0] = a0; p[0][grp][f0 + 1] = a1; p[0][grp][f0 + 2] = a2; p[0][grp][f0 + 3] = a3;
    p[1][grp][f0] = h0; p[1][grp][f0 + 1] = h1s; p[1][grp][f0 + 2] = h2; p[1][grp][f0 + 3] = h3;
    p[2][grp][f0] = c0; p[2][grp][f0 + 1] = c1; p[2][grp][f0 + 2] = c2; p[2][grp][f0 + 3] = c3;
    __syncthreads();

    if (tid < 192) {
        const int arr = tid >> 6, f = tid & 63;
        float s = 0.f;
        #pragma unroll
        for (int i = 0; i < 16; i++) s += p[arr][i][f];
        q[arr][f] = s;
    }
    __syncthreads();

    if (tid < 10) {
        const int c = tid;
        float acc = b0[c] + b1[c] + b2[c];
        for (int k = 0; k < 64; k++) {
            acc = fmaf(q[0][k], w0[k * 10 + c], acc);
            acc = fmaf(q[1][k], w1[k * 10 + c], acc);
            acc = fmaf(q[2][k], w2[k * 10 + c], acc);
        }
        out[(size_t)g * 10 + c] = acc;
    }
}

extern "C" void kernel_launch(void* const* d_in, const int* in_sizes, int n_in,
                              void* d_out, int out_size, void* d_ws, size_t ws_size,
                              hipStream_t stream)
{
    const float* x     = (const float*)d_in[0];
    const int*   edge  = (const int*)d_in[1];
    const int*   batch = (const int*)d_in[2];
    const int N = in_sizes[0] / 64;
    const int E = in_sizes[1] / 2;
    const int G = out_size / 10;
    const int* src = edge;
    const int* dst = edge + E;
    const int NB = (N + 255) / 256;

    const float* c_w1[2]  = {(const float*)d_in[3],  (const float*)d_in[11]};
    const float* c_b1[2]  = {(const float*)d_in[4],  (const float*)d_in[12]};
    const float* c_g1[2]  = {(const float*)d_in[5],  (const float*)d_in[13]};
    const float* c_be1[2] = {(const float*)d_in[6],  (const float*)d_in[14]};
    const float* c_w2[2]  = {(const float*)d_in[7],  (const float*)d_in[15]};
    const float* c_b2[2]  = {(const float*)d_in[8],  (const float*)d_in[16]};
    const float* bn_g[2]  = {(const float*)d_in[9],  (const float*)d_in[17]};
    const float* bn_b[2]  = {(const float*)d_in[10], (const float*)d_in[18]};
    const float* lw[3]    = {(const float*)d_in[19], (const float*)d_in[21], (const float*)d_in[23]};
    const float* lb[3]    = {(const float*)d_in[20], (const float*)d_in[22], (const float*)d_in[24]};

    float* out = (float*)d_out;
    const size_t nh1 = (size_t)(N + 1) * 64;   // node buffers have +1 zero pad row
    const int GRID_MLP = 256;
    const int RPB = (N + GRID_MLP - 1) / GRID_MLP;

    // workspace layout
    bf16*  zb    = (bf16*)d_ws;                // nh1 (L0 z/y buffer, in-place)
    bf16*  wb    = zb + nh1;                   // nh1 (L1 z/y buffer, in-place)
    bf16*  xb    = wb + nh1;                   // nh1 (x cast, row N = 0)
    bf16*  hb    = xb + nh1;                   // nh1 (h1, row N = 0)
    float* scsh  = (float*)(hb + nh1);         // 512 (scB/shB live at +384/+448)
    float* pstat  = scsh + 512;                // GRID_MLP x 128
    float* pstat2 = pstat + (size_t)GRID_MLP * 128;
    int*   rowptr = (int*)(pstat2 + (size_t)GRID_MLP * 128);  // N
    int*   rowend = rowptr + N;                // N
    int*   adj    = rowend + N;                // NB*PCAP (8-padded rows)
    int*   tmp    = adj + (size_t)NB * PCAP;   // NB*CAP
    int*   bcur   = tmp + (size_t)NB * CAP;    // NB

    float* scB = scsh + 384; float* shB = scsh + 448;

    float invN = 1.0f / (float)N;
    const int binGrid  = (E + CHUNK - 1) / CHUNK;
    const int aggGrid  = (N + 15) / 16;
    const int n4       = N * 16;               // cast region in 4-elem chunks
    const int total4   = (N + 1) * 16;         // + pad row
    const int ewGrid   = (total4 + 255) / 256;

    // ---- init+cast, CSR build (fixed-stride buckets, 8-padded rows) ----
    initcast_k<<<ewGrid, 256, 0, stream>>>(x, xb, hb, n4, total4, bcur, NB);
    binscatter_k<<<binGrid, 256, 0, stream>>>(src, dst, bcur, tmp, E, NB);
    csr_k<<<NB, 256, 0, stream>>>(bcur, tmp, rowptr, rowend, adj, N);

    // ---- layer 0: aggregate + fused MLP (writes y0 in-place and h1) ----
    aggregate_k<<<aggGrid, 256, 0, stream>>>(xb, rowptr, rowend, adj, zb, N);
    {
        const bf16* A = zb; bf16* Y = zb; bf16* H = hb;
        const float *W1 = c_w1[0], *B1 = c_b1[0], *G1 = c_g1[0], *BE1 = c_be1[0];
        const float *W2 = c_w2[0], *B2 = c_b2[0], *G2 = bn_g[0], *BE2 = bn_b[0];
        int Nv = N, RPBv = RPB, GRIDv = GRID_MLP;
        void* args[] = {(void*)&A, (void*)&Y, (void*)&H,
                        (void*)&W1, (void*)&B1, (void*)&G1, (void*)&BE1,
                        (void*)&W2, (void*)&B2, (void*)&G2, (void*)&BE2,
                        (void*)&pstat, (void*)&pstat2, (void*)&scB, (void*)&shB,
                        (void*)&Nv, (void*)&RPBv, (void*)&invN, (void*)&GRIDv};
        hipLaunchCooperativeKernel((const void*)mlp_k<0>, dim3(GRID_MLP), dim3(256),
                                   args, 0, stream);
    }

    // ---- layer 1: aggregate + fused MLP (writes y1 in-place, emits scB/shB) ----
    aggregate_k<<<aggGrid, 256, 0, stream>>>(hb, rowptr, rowend, adj, wb, N);
    {
        const bf16* A = wb; bf16* Y = wb; bf16* H = hb;   // H unused for L=1
        const float *W1 = c_w1[1], *B1 = c_b1[1], *G1 = c_g1[1], *BE1 = c_be1[1];
        const float *W2 = c_w2[1], *B2 = c_b2[1], *G2 = bn_g[1], *BE2 = bn_b[1];
        int Nv = N, RPBv = RPB, GRIDv = GRID_MLP;
        void* args[] = {(void*)&A, (void*)&Y, (void*)&H,
                        (void*)&W1, (void*)&B1, (void*)&G1, (void*)&BE1,
                        (void*)&W2, (void*)&B2, (void*)&G2, (void*)&BE2,
                        (void*)&pstat, (void*)&pstat2, (void*)&scB, (void*)&shB,
                        (void*)&Nv, (void*)&RPBv, (void*)&invN, (void*)&GRIDv};
        hipLaunchCooperativeKernel((const void*)mlp_k<1>, dim3(GRID_MLP), dim3(256),
                                   args, 0, stream);
    }

    // ---- pooled readout (h2 affine+relu fused) ----
    pool_readout_k<<<G, 256, 0, stream>>>(xb, hb, wb, batch,
                                          scB, shB,
                                          lw[0], lb[0], lw[1], lb[1], lw[2], lb[2],
                                          out, N);
}

// Round 6
// 675.749 us; speedup vs baseline: 1.0014x; 1.0014x over previous
//
#include <hip/hip_runtime.h>
#include <hip/hip_bf16.h>

#define BN_EPS 1e-5f
#define NBMAX 512      // max buckets (N/256)
#define CHUNK 4096     // edges per binning block
#define CAP   5120     // fixed per-bucket capacity (mean 4096 + 16 sigma)
#define PCAP  7168     // padded per-bucket adj capacity (CAP + 256*7 = 6912 <= 7168, mult of 8)

typedef __hip_bfloat16 bf16;
typedef __attribute__((ext_vector_type(8))) short short8;
typedef __attribute__((ext_vector_type(4))) float f32x4;

__device__ __forceinline__ float b2f(bf16 v) { return __bfloat162float(v); }
__device__ __forceinline__ bf16 f2b(float v) { return __float2bfloat16(v); }
__device__ __forceinline__ float bl(unsigned u) { return __uint_as_float(u << 16); }
__device__ __forceinline__ float bh(unsigned u) { return __uint_as_float(u & 0xffff0000u); }
__device__ __forceinline__ unsigned pack2(float x, float y) {
    union { bf16 b[2]; unsigned u; } p;
    p.b[0] = f2b(x); p.b[1] = f2b(y);
    return p.u;
}
__device__ __forceinline__ float bs2f(short s) {
    return __uint_as_float(((unsigned)(unsigned short)s) << 16);
}
__device__ __forceinline__ short f2bs(float v) {
    bf16 b = f2b(v);
    return *reinterpret_cast<short*>(&b);
}

// ============ init bcur + counters + cast x -> bf16; row N of xb zeroed ============
__global__ __launch_bounds__(256) void initcast_k(
    const float* __restrict__ in, bf16* __restrict__ out, int n4, int total4,
    int* __restrict__ bcur, int NB, int* __restrict__ cnts)
{
    if (blockIdx.x == 0) {
        for (int i = threadIdx.x; i < NB; i += 256) bcur[i] = i * CAP;
        if (threadIdx.x < 4) cnts[threadIdx.x] = 0;   // last-block counters
    }
    int i = blockIdx.x * 256 + threadIdx.x;
    if (i >= total4) return;
    if (i < n4) {
        float4 v = ((const float4*)in)[i];
        union { ushort4 u; bf16 b[4]; } p;
        p.b[0] = f2b(v.x); p.b[1] = f2b(v.y); p.b[2] = f2b(v.z); p.b[3] = f2b(v.w);
        ((ushort4*)out)[i] = p.u;
    } else {
        ushort4 z; z.x = 0; z.y = 0; z.z = 0; z.w = 0;
        ((ushort4*)out)[i] = z;   // zero pad row N
    }
}

// ============ binscatter: group edges by bucket in LDS, write coalesced runs ====
__global__ __launch_bounds__(256) void binscatter_k(
    const int* __restrict__ src, const int* __restrict__ dst,
    int* __restrict__ bcur, int* __restrict__ tmp, int E, int NB)
{
    __shared__ int hist[NBMAX];
    __shared__ int loff[NBMAX];
    __shared__ int gb[NBMAX];
    __shared__ int lcur[NBMAX];
    __shared__ int staged[CHUNK];
    __shared__ unsigned short sb[CHUNK];
    __shared__ int ssc[256];
    const int t = threadIdx.x;
    for (int i = t; i < NB; i += 256) { hist[i] = 0; lcur[i] = 0; }
    __syncthreads();
    const int base = blockIdx.x * CHUNK;
    const int lim = min(CHUNK, E - base);
    int myb[16], myw[16];
    int cnt = 0;
    for (int i = t; i < lim; i += 256) {
        int d = dst[base + i];
        int s_ = src[base + i];
        int b = d >> 8;
        myb[cnt] = b;
        myw[cnt] = (s_ << 8) | (d & 255);
        cnt++;
        atomicAdd(&hist[b], 1);
    }
    __syncthreads();
    int v0 = (2 * t     < NB) ? hist[2 * t]     : 0;
    int v1 = (2 * t + 1 < NB) ? hist[2 * t + 1] : 0;
    ssc[t] = v0 + v1;
    __syncthreads();
    for (int off = 1; off < 256; off <<= 1) {
        int a = (t >= off) ? ssc[t - off] : 0;
        __syncthreads();
        ssc[t] += a;
        __syncthreads();
    }
    int excl = ssc[t] - (v0 + v1);
    if (2 * t < NB)     loff[2 * t] = excl;
    if (2 * t + 1 < NB) loff[2 * t + 1] = excl + v0;
    __syncthreads();
    for (int b = t; b < NB; b += 256)
        if (hist[b] > 0) gb[b] = atomicAdd(&bcur[b], hist[b]);
    for (int i = 0; i < cnt; i++) {
        int b = myb[i];
        int p = loff[b] + atomicAdd(&lcur[b], 1);
        staged[p] = myw[i];
        sb[p] = (unsigned short)b;
    }
    __syncthreads();
    for (int i = t; i < lim; i += 256) {
        int b = sb[i];
        tmp[gb[b] + (i - loff[b])] = staged[i];
    }
}

// ============ csr: per bucket counting sort -> 8-padded rows (pad idx = N) ======
__global__ __launch_bounds__(256) void csr_k(
    const int* __restrict__ bcur, const int* __restrict__ tmp,
    int* __restrict__ rowptr, int* __restrict__ rowend,
    int* __restrict__ adj, int N)
{
    __shared__ int hist[256], pfx[256], cur[256], ssc[256];
    __shared__ int sadj[PCAP];
    const int b = blockIdx.x, t = threadIdx.x;
    const int lo = b * CAP;          // tmp base (unpadded)
    const int plo = b * PCAP;        // adj base (padded)
    const int cnt = min(bcur[b] - lo, CAP);
    hist[t] = 0; cur[t] = 0;
    __syncthreads();
    for (int i = t; i < cnt; i += 256)
        atomicAdd(&hist[tmp[lo + i] & 255], 1);
    __syncthreads();
    const int v = hist[t];
    const int pv = (v + 7) & ~7;     // pad each row to multiple of 8
    ssc[t] = pv;
    __syncthreads();
    for (int off = 1; off < 256; off <<= 1) {
        int a = (t >= off) ? ssc[t - off] : 0;
        __syncthreads();
        ssc[t] += a;
        __syncthreads();
    }
    const int myp = ssc[t] - pv;
    pfx[t] = myp;
    const int node = b * 256 + t;
    if (node < N) {
        rowptr[node] = plo + myp;
        rowend[node] = plo + myp + pv;
    }
    __syncthreads();
    const int pcnt = ssc[255];       // <= CAP + 256*7 = 6912 <= PCAP always
    for (int i = t; i < cnt; i += 256) {
        int w = tmp[lo + i];
        int d = w & 255;
        int p = pfx[d] + atomicAdd(&cur[d], 1);
        sadj[p] = w >> 8;
    }
    __syncthreads();
    for (int i = v; i < pv; i++) sadj[myp + i] = N;   // pad -> zero row
    __syncthreads();
    for (int i = t; i < pcnt; i += 256) adj[plo + i] = sadj[i];
}

// ========== aggregation: z[n] = h[n] + sum_m h[m]; rows 8-padded, branch-free ==
// 16 lanes per node, dwordx2 loads: one gather instr = full 128B row per group,
// 512B per wave64 instr. Batch of 8 gathers in flight; next adj batch prefetched.
__global__ __launch_bounds__(256, 4) void aggregate_k(
    const bf16* __restrict__ h, const int* __restrict__ rowptr,
    const int* __restrict__ rowend, const int* __restrict__ adj,
    bf16* __restrict__ z, int N)
{
    const int lane16 = threadIdx.x & 15;
    const int n = blockIdx.x * 16 + (threadIdx.x >> 4);
    if (n >= N) return;
    const char* hb_ = (const char*)h;   // row stride 128B
    const int b = rowptr[n], e = rowend[n];

    uint2 u = *(const uint2*)(hb_ + ((size_t)n << 7) + (lane16 << 3));
    float s0 = bl(u.x), s1 = bh(u.x), s2 = bl(u.y), s3 = bh(u.y);

    int m[8];
    if (b < e) {
        #pragma unroll
        for (int k = 0; k < 8; k++) m[k] = adj[b + k];
    }
    for (int i = b; i < e; ) {
        uint2 w[8];
        #pragma unroll
        for (int k = 0; k < 8; k++)
            w[k] = *(const uint2*)(hb_ + (((size_t)(unsigned)m[k]) << 7) + (lane16 << 3));
        const int inext = i + 8;
        if (inext < e) {
            #pragma unroll
            for (int k = 0; k < 8; k++) m[k] = adj[inext + k];
        }
        #pragma unroll
        for (int k = 0; k < 8; k++) {
            s0 += bl(w[k].x); s1 += bh(w[k].x);
            s2 += bl(w[k].y); s3 += bh(w[k].y);
        }
        i = inext;
    }
    uint2 o;
    o.x = pack2(s0, s1);
    o.y = pack2(s2, s3);
    *(uint2*)((char*)z + ((size_t)n << 7) + (lane16 << 3)) = o;
}

// ========== elementwise act: h = relu(y*sc+sh); row N zeroed (pad row) ==========
__global__ __launch_bounds__(256) void ewact_k(
    const bf16* __restrict__ y, const float* __restrict__ sc,
    const float* __restrict__ sh, bf16* __restrict__ h, int N)
{
    const int idx = blockIdx.x * 256 + threadIdx.x;   // one thread = 8 elems
    const int total = (N + 1) * 8;
    if (idx >= total) return;
    short8 v;
    if (idx < N * 8) {
        const int f0 = (idx & 7) * 8;
        v = *(const short8*)(y + (size_t)idx * 8);
        #pragma unroll
        for (int j = 0; j < 8; j++)
            v[j] = f2bs(fmaxf(fmaf(bs2f(v[j]), sc[f0 + j], sh[f0 + j]), 0.f));
    } else {
        #pragma unroll
        for (int j = 0; j < 8; j++) v[j] = 0;
    }
    *(short8*)(h + (size_t)idx * 8) = v;
}

// ---------------- MFMA GEMM (bf16 in/out, f32 acc) ----------------
// C[N x 64] = act(A) @ W + bias.  MODE 0: act = id;  MODE 1: act = relu(A*sc+sh).
// 256 thr = 4 waves; 128 rows/block; per-block stats -> pstat (no atomics).
// Last-arriving block (counter) reduces pstat -> scout/shout (replaces bn_reduce
// launch; rocPRIM-style threadfence + atomic counter pattern).
template<int MODE>
__global__ __launch_bounds__(256) void gemm64_k(
    const bf16* __restrict__ A,
    const float* __restrict__ scin, const float* __restrict__ shin,
    const float* __restrict__ W, const float* __restrict__ bias,
    bf16* __restrict__ out, float* __restrict__ pstat, int nrows,
    const float* __restrict__ gr, const float* __restrict__ be, float invN,
    float* __restrict__ scout, float* __restrict__ shout,
    int* __restrict__ counter, int nblk)
{
    __shared__ bf16 sWt[64][72];     // transposed W (n-major)
    __shared__ bf16 sC[128][68];     // C tile; 136B rows: 8B-aligned, 2-way bank alias
    __shared__ float sSc[64], sSh[64], sB[64];
    __shared__ float sredS[64][17], sredQ[64][17];
    __shared__ float red2[2][128];
    __shared__ int isLast;
    const int tid = threadIdx.x;

    if (tid < 64) {
        sB[tid] = bias[tid];
        if (MODE == 1) { sSc[tid] = scin[tid]; sSh[tid] = shin[tid]; }
    }
    for (int i = tid; i < 4096; i += 256) {
        int k = i >> 6, n = i & 63;
        sWt[n][k] = f2b(W[i]);
    }
    __syncthreads();

    const int wave = tid >> 6, lane = tid & 63;
    const int quad = lane >> 4, l16 = lane & 15;
    const int row0 = blockIdx.x * 128 + wave * 32;

    short8 a[2][2];
    #pragma unroll
    for (int rt = 0; rt < 2; rt++) {
        int r = row0 + rt * 16 + l16;
        int rr = min(r, nrows - 1);
        const bf16* arow = A + (size_t)rr * 64;
        a[rt][0] = *(const short8*)(arow + quad * 8);
        a[rt][1] = *(const short8*)(arow + 32 + quad * 8);
        if (MODE == 1) {
            #pragma unroll
            for (int j = 0; j < 8; j++) {
                int f0 = quad * 8 + j;
                a[rt][0][j] = f2bs(fmaxf(fmaf(bs2f(a[rt][0][j]), sSc[f0], sSh[f0]), 0.f));
                int f1 = 32 + f0;
                a[rt][1][j] = f2bs(fmaxf(fmaf(bs2f(a[rt][1][j]), sSc[f1], sSh[f1]), 0.f));
            }
        }
    }

    float psS[4], psQ[4];
    #pragma unroll
    for (int t = 0; t < 4; t++) { psS[t] = 0.f; psQ[t] = 0.f; }

    #pragma unroll
    for (int t = 0; t < 4; t++) {
        const int n = t * 16 + l16;
        short8 b0 = *(const short8*)&sWt[n][quad * 8];
        short8 b1 = *(const short8*)&sWt[n][32 + quad * 8];
        const float bn_ = sB[n];
        #pragma unroll
        for (int rt = 0; rt < 2; rt++) {
            f32x4 acc = {0.f, 0.f, 0.f, 0.f};
            acc = __builtin_amdgcn_mfma_f32_16x16x32_bf16(a[rt][0], b0, acc, 0, 0, 0);
            acc = __builtin_amdgcn_mfma_f32_16x16x32_bf16(a[rt][1], b1, acc, 0, 0, 0);
            #pragma unroll
            for (int reg = 0; reg < 4; reg++) {
                const int lr = wave * 32 + rt * 16 + quad * 4 + reg;  // local row
                float v = acc[reg] + bn_;
                sC[lr][n] = f2b(v);
                if (row0 + rt * 16 + quad * 4 + reg < nrows) {
                    psS[t] += v;
                    psQ[t] = fmaf(v, v, psQ[t]);
                }
            }
        }
    }

    #pragma unroll
    for (int t = 0; t < 4; t++) {
        sredS[t * 16 + l16][wave * 4 + quad] = psS[t];
        sredQ[t * 16 + l16][wave * 4 + quad] = psQ[t];
    }
    __syncthreads();

    // coalesced C-tile writeout: 2048 ushort4 chunks (128 rows x 16)
    const int gbase = blockIdx.x * 128;
    #pragma unroll
    for (int it = 0; it < 8; it++) {
        int idx = it * 256 + tid;
        int r = idx >> 4, c4 = idx & 15;
        if (gbase + r < nrows) {
            ushort4 v = *(const ushort4*)&sC[r][c4 * 4];
            *(ushort4*)(out + (size_t)(gbase + r) * 64 + c4 * 4) = v;
        }
    }

    if (tid < 128) {
        const int c = tid & 63;
        const float* p = (tid < 64) ? &sredS[c][0] : &sredQ[c][0];
        float s = 0.f;
        #pragma unroll
        for (int i = 0; i < 16; i++) s += p[i];
        pstat[(size_t)blockIdx.x * 128 + (tid < 64 ? c : 64 + c)] = s;
    }

    // ---- last-block BN reduce: pstat -> scout/shout ----
    __threadfence();
    __syncthreads();
    if (tid == 0) isLast = (atomicAdd(counter, 1) == nblk - 1);
    __syncthreads();
    if (!isLast) return;
    __threadfence();
    const int c = tid & 127, part = tid >> 7;
    float s = 0.f;
    int b = part;
    for (; b + 8 <= nblk; b += 8) {
        float x0 = pstat[(size_t)(b)     * 128 + c];
        float x1 = pstat[(size_t)(b + 2) * 128 + c];
        float x2 = pstat[(size_t)(b + 4) * 128 + c];
        float x3 = pstat[(size_t)(b + 6) * 128 + c];
        s += (x0 + x1) + (x2 + x3);
    }
    for (; b < nblk; b += 2) s += pstat[(size_t)b * 128 + c];
    red2[part][c] = s;
    __syncthreads();
    if (tid < 64) {
        float S = red2[0][tid] + red2[1][tid];
        float Q = red2[0][64 + tid] + red2[1][64 + tid];
        float m = S * invN;
        float var = Q * invN - m * m;
        float sc_ = gr[tid] * rsqrtf(var + BN_EPS);
        scout[tid] = sc_;
        shout[tid] = be[tid] - m * sc_;
    }
}

// ---------------- pooled readout; h1 pre-materialized, h2 affine on the fly ------
// 16 groups x 16 lanes; uint2 loads (8B/lane), 4 features per lane.
__global__ __launch_bounds__(256) void pool_readout_k(
    const bf16* __restrict__ xb, const bf16* __restrict__ h1,
    const bf16* __restrict__ y1, const int* __restrict__ batch,
    const float* __restrict__ scB, const float* __restrict__ shB,
    const float* __restrict__ w0, const float* __restrict__ b0,
    const float* __restrict__ w1, const float* __restrict__ b1,
    const float* __restrict__ w2, const float* __restrict__ b2,
    float* __restrict__ out, int Nn)
{
    __shared__ float sB2[2][64];
    __shared__ float p[3][16][64];
    __shared__ float q[3][64];
    const int tid = threadIdx.x;
    if (tid < 64) { sB2[0][tid] = scB[tid]; sB2[1][tid] = shB[tid]; }
    __syncthreads();

    const int g = blockIdx.x;
    int lo = 0, hi = Nn;
    while (lo < hi) { int mid = (lo + hi) >> 1; if (batch[mid] < g) lo = mid + 1; else hi = mid; }
    const int start = lo;
    hi = Nn;
    while (lo < hi) { int mid = (lo + hi) >> 1; if (batch[mid] <= g) lo = mid + 1; else hi = mid; }
    const int end = lo;

    const int l16 = tid & 15, grp = tid >> 4;
    const int f0 = l16 * 4;
    const float scB0 = sB2[0][f0],      shB0 = sB2[1][f0];
    const float scB1 = sB2[0][f0 + 1],  shB1 = sB2[1][f0 + 1];
    const float scB2_ = sB2[0][f0 + 2], shB2_ = sB2[1][f0 + 2];
    const float scB3 = sB2[0][f0 + 3],  shB3 = sB2[1][f0 + 3];

    float a0 = 0.f, a1 = 0.f, a2 = 0.f, a3 = 0.f;
    float h0 = 0.f, h1s = 0.f, h2 = 0.f, h3 = 0.f;
    float c0 = 0.f, c1 = 0.f, c2 = 0.f, c3 = 0.f;
    for (int i = start + grp; i < end; i += 16) {
        const size_t ro = (size_t)i * 16 + l16;
        uint2 ux = ((const uint2*)xb)[ro];
        uint2 u0 = ((const uint2*)h1)[ro];
        uint2 u1 = ((const uint2*)y1)[ro];
        a0 += bl(ux.x); a1 += bh(ux.x); a2 += bl(ux.y); a3 += bh(ux.y);
        h0 += bl(u0.x); h1s += bh(u0.x); h2 += bl(u0.y); h3 += bh(u0.y);
        c0 += fmaxf(fmaf(bl(u1.x), scB0, shB0), 0.f);
        c1 += fmaxf(fmaf(bh(u1.x), scB1, shB1), 0.f);
        c2 += fmaxf(fmaf(bl(u1.y), scB2_, shB2_), 0.f);
        c3 += fmaxf(fmaf(bh(u1.y), scB3, shB3), 0.f);
    }
    p[0][grp][f0] = a0; p[0][grp][f0 + 1] = a1; p[0][grp][f0 + 2] = a2; p[0][grp][f0 + 3] = a3;
    p[1][grp][f0] = h0; p[1][grp][f0 + 1] = h1s; p[1][grp][f0 + 2] = h2; p[1][grp][f0 + 3] = h3;
    p[2][grp][f0] = c0; p[2][grp][f0 + 1] = c1; p[2][grp][f0 + 2] = c2; p[2][grp][f0 + 3] = c3;
    __syncthreads();

    if (tid < 192) {
        const int arr = tid >> 6, f = tid & 63;
        float s = 0.f;
        #pragma unroll
        for (int i = 0; i < 16; i++) s += p[arr][i][f];
        q[arr][f] = s;
    }
    __syncthreads();

    if (tid < 10) {
        const int c = tid;
        float acc = b0[c] + b1[c] + b2[c];
        for (int k = 0; k < 64; k++) {
            acc = fmaf(q[0][k], w0[k * 10 + c], acc);
            acc = fmaf(q[1][k], w1[k * 10 + c], acc);
            acc = fmaf(q[2][k], w2[k * 10 + c], acc);
        }
        out[(size_t)g * 10 + c] = acc;
    }
}

extern "C" void kernel_launch(void* const* d_in, const int* in_sizes, int n_in,
                              void* d_out, int out_size, void* d_ws, size_t ws_size,
                              hipStream_t stream)
{
    const float* x     = (const float*)d_in[0];
    const int*   edge  = (const int*)d_in[1];
    const int*   batch = (const int*)d_in[2];
    const int N = in_sizes[0] / 64;
    const int E = in_sizes[1] / 2;
    const int G = out_size / 10;
    const int* src = edge;
    const int* dst = edge + E;
    const int NB = (N + 255) / 256;

    const float* c_w1[2]  = {(const float*)d_in[3],  (const float*)d_in[11]};
    const float* c_b1[2]  = {(const float*)d_in[4],  (const float*)d_in[12]};
    const float* c_g1[2]  = {(const float*)d_in[5],  (const float*)d_in[13]};
    const float* c_be1[2] = {(const float*)d_in[6],  (const float*)d_in[14]};
    const float* c_w2[2]  = {(const float*)d_in[7],  (const float*)d_in[15]};
    const float* c_b2[2]  = {(const float*)d_in[8],  (const float*)d_in[16]};
    const float* bn_g[2]  = {(const float*)d_in[9],  (const float*)d_in[17]};
    const float* bn_b[2]  = {(const float*)d_in[10], (const float*)d_in[18]};
    const float* lw[3]    = {(const float*)d_in[19], (const float*)d_in[21], (const float*)d_in[23]};
    const float* lb[3]    = {(const float*)d_in[20], (const float*)d_in[22], (const float*)d_in[24]};

    float* out = (float*)d_out;
    const size_t nh1 = (size_t)(N + 1) * 64;   // node buffers have +1 zero pad row
    const int PG = (N + 127) / 128;   // gemm grid

    // workspace layout
    bf16*  zb    = (bf16*)d_ws;                // nh1 (L0 t/y buffer, in-place)
    bf16*  wb    = zb + nh1;                   // nh1 (L1 t/y buffer, in-place)
    bf16*  xb    = wb + nh1;                   // nh1 (x cast, row N = 0)
    bf16*  hb    = xb + nh1;                   // nh1 (h1 = act(y0), row N = 0)
    float* scsh  = (float*)(hb + nh1);         // 8 x 64
    float* pstat = scsh + 512;                 // PG x 128
    int*   rowptr = (int*)(pstat + (size_t)PG * 128);  // N
    int*   rowend = rowptr + N;                // N
    int*   adj    = rowend + N;                // NB*PCAP (8-padded rows)
    int*   tmp    = adj + (size_t)NB * PCAP;   // NB*CAP
    int*   bcur   = tmp + (size_t)NB * CAP;    // NB
    int*   cnts   = bcur + NB;                 // 4 last-block counters

    float* sc0 = scsh;       float* sh0 = scsh + 64;
    float* scA = scsh + 128; float* shA = scsh + 192;
    float* sc2 = scsh + 256; float* sh2 = scsh + 320;
    float* scB = scsh + 384; float* shB = scsh + 448;

    const float invN = 1.0f / (float)N;
    const int binGrid  = (E + CHUNK - 1) / CHUNK;
    const int aggGrid  = (N + 15) / 16;
    const int n4       = N * 16;               // cast region in 4-elem chunks
    const int total4   = (N + 1) * 16;         // + pad row
    const int ewGrid   = (total4 + 255) / 256;
    const int actGrid  = ((N + 1) * 8 + 255) / 256;

    // ---- init+cast, CSR build (fixed-stride buckets, 8-padded rows) ----
    initcast_k<<<ewGrid, 256, 0, stream>>>(x, xb, n4, total4, bcur, NB, cnts);
    binscatter_k<<<binGrid, 256, 0, stream>>>(src, dst, bcur, tmp, E, NB);
    csr_k<<<NB, 256, 0, stream>>>(bcur, tmp, rowptr, rowend, adj, N);

    // ---- layer 0 ----
    aggregate_k<<<aggGrid, 256, 0, stream>>>(xb, rowptr, rowend, adj, zb, N);
    gemm64_k<0><<<PG, 256, 0, stream>>>(zb, nullptr, nullptr,
                                        c_w1[0], c_b1[0], zb, pstat, N,
                                        c_g1[0], c_be1[0], invN, sc0, sh0, cnts + 0, PG);
    gemm64_k<1><<<PG, 256, 0, stream>>>(zb, sc0, sh0,
                                        c_w2[0], c_b2[0], zb, pstat, N,
                                        bn_g[0], bn_b[0], invN, scA, shA, cnts + 1, PG);

    // ---- h1 = relu(affine(y0)) materialized once (pad row zeroed) ----
    ewact_k<<<actGrid, 256, 0, stream>>>(zb, scA, shA, hb, N);

    // ---- layer 1 ----
    aggregate_k<<<aggGrid, 256, 0, stream>>>(hb, rowptr, rowend, adj, wb, N);
    gemm64_k<0><<<PG, 256, 0, stream>>>(wb, nullptr, nullptr,
                                        c_w1[1], c_b1[1], wb, pstat, N,
                                        c_g1[1], c_be1[1], invN, sc2, sh2, cnts + 2, PG);
    gemm64_k<1><<<PG, 256, 0, stream>>>(wb, sc2, sh2,
                                        c_w2[1], c_b2[1], wb, pstat, N,
                                        bn_g[1], bn_b[1], invN, scB, shB, cnts + 3, PG);

    // ---- pooled readout (h2 affine+relu fused) ----
    pool_readout_k<<<G, 256, 0, stream>>>(xb, hb, wb, batch,
                                          scB, shB,
                                          lw[0], lb[0], lw[1], lb[1], lw[2], lb[2],
                                          out, N);
}

// Round 7
// 287.812 us; speedup vs baseline: 2.3511x; 2.3479x over previous
//
#include <hip/hip_runtime.h>
#include <hip/hip_bf16.h>

#define BN_EPS 1e-5f
#define NBMAX 512      // max buckets (N/256)
#define CHUNK 4096     // edges per binning block
#define CAP   5120     // fixed per-bucket capacity (mean 4096 + 16 sigma)
#define PCAP  7168     // padded per-bucket adj capacity (CAP + 256*7 = 6912 <= 7168, mult of 8)

typedef __hip_bfloat16 bf16;
typedef __attribute__((ext_vector_type(8))) short short8;
typedef __attribute__((ext_vector_type(4))) float f32x4;

__device__ __forceinline__ float b2f(bf16 v) { return __bfloat162float(v); }
__device__ __forceinline__ bf16 f2b(float v) { return __float2bfloat16(v); }
__device__ __forceinline__ float bl(unsigned u) { return __uint_as_float(u << 16); }
__device__ __forceinline__ float bh(unsigned u) { return __uint_as_float(u & 0xffff0000u); }
__device__ __forceinline__ unsigned pack2(float x, float y) {
    union { bf16 b[2]; unsigned u; } p;
    p.b[0] = f2b(x); p.b[1] = f2b(y);
    return p.u;
}
__device__ __forceinline__ float bs2f(short s) {
    return __uint_as_float(((unsigned)(unsigned short)s) << 16);
}
__device__ __forceinline__ short f2bs(float v) {
    bf16 b = f2b(v);
    return *reinterpret_cast<short*>(&b);
}

// ============ init bcur (fixed-stride bases) + cast x -> bf16; row N zeroed ======
__global__ __launch_bounds__(256) void initcast_k(
    const float* __restrict__ in, bf16* __restrict__ out, int n4, int total4,
    int* __restrict__ bcur, int NB)
{
    if (blockIdx.x == 0) {
        for (int i = threadIdx.x; i < NB; i += 256) bcur[i] = i * CAP;
    }
    int i = blockIdx.x * 256 + threadIdx.x;
    if (i >= total4) return;
    if (i < n4) {
        float4 v = ((const float4*)in)[i];
        union { ushort4 u; bf16 b[4]; } p;
        p.b[0] = f2b(v.x); p.b[1] = f2b(v.y); p.b[2] = f2b(v.z); p.b[3] = f2b(v.w);
        ((ushort4*)out)[i] = p.u;
    } else {
        ushort4 z; z.x = 0; z.y = 0; z.z = 0; z.w = 0;
        ((ushort4*)out)[i] = z;   // zero pad row N
    }
}

// ============ binscatter: group edges by bucket in LDS, write coalesced runs ====
__global__ __launch_bounds__(256) void binscatter_k(
    const int* __restrict__ src, const int* __restrict__ dst,
    int* __restrict__ bcur, int* __restrict__ tmp, int E, int NB)
{
    __shared__ int hist[NBMAX];
    __shared__ int loff[NBMAX];
    __shared__ int gb[NBMAX];
    __shared__ int lcur[NBMAX];
    __shared__ int staged[CHUNK];
    __shared__ unsigned short sb[CHUNK];
    __shared__ int ssc[256];
    const int t = threadIdx.x;
    for (int i = t; i < NB; i += 256) { hist[i] = 0; lcur[i] = 0; }
    __syncthreads();
    const int base = blockIdx.x * CHUNK;
    const int lim = min(CHUNK, E - base);
    int myb[16], myw[16];
    int cnt = 0;
    for (int i = t; i < lim; i += 256) {
        int d = dst[base + i];
        int s_ = src[base + i];
        int b = d >> 8;
        myb[cnt] = b;
        myw[cnt] = (s_ << 8) | (d & 255);
        cnt++;
        atomicAdd(&hist[b], 1);
    }
    __syncthreads();
    int v0 = (2 * t     < NB) ? hist[2 * t]     : 0;
    int v1 = (2 * t + 1 < NB) ? hist[2 * t + 1] : 0;
    ssc[t] = v0 + v1;
    __syncthreads();
    for (int off = 1; off < 256; off <<= 1) {
        int a = (t >= off) ? ssc[t - off] : 0;
        __syncthreads();
        ssc[t] += a;
        __syncthreads();
    }
    int excl = ssc[t] - (v0 + v1);
    if (2 * t < NB)     loff[2 * t] = excl;
    if (2 * t + 1 < NB) loff[2 * t + 1] = excl + v0;
    __syncthreads();
    for (int b = t; b < NB; b += 256)
        if (hist[b] > 0) gb[b] = atomicAdd(&bcur[b], hist[b]);
    for (int i = 0; i < cnt; i++) {
        int b = myb[i];
        int p = loff[b] + atomicAdd(&lcur[b], 1);
        staged[p] = myw[i];
        sb[p] = (unsigned short)b;
    }
    __syncthreads();
    for (int i = t; i < lim; i += 256) {
        int b = sb[i];
        tmp[gb[b] + (i - loff[b])] = staged[i];
    }
}

// ============ csr: per bucket counting sort -> 8-padded rows (pad idx = N) ======
__global__ __launch_bounds__(256) void csr_k(
    const int* __restrict__ bcur, const int* __restrict__ tmp,
    int* __restrict__ rowptr, int* __restrict__ rowend,
    int* __restrict__ adj, int N)
{
    __shared__ int hist[256], pfx[256], cur[256], ssc[256];
    __shared__ int sadj[PCAP];
    const int b = blockIdx.x, t = threadIdx.x;
    const int lo = b * CAP;          // tmp base (unpadded)
    const int plo = b * PCAP;        // adj base (padded)
    const int cnt = min(bcur[b] - lo, CAP);
    hist[t] = 0; cur[t] = 0;
    __syncthreads();
    for (int i = t; i < cnt; i += 256)
        atomicAdd(&hist[tmp[lo + i] & 255], 1);
    __syncthreads();
    const int v = hist[t];
    const int pv = (v + 7) & ~7;     // pad each row to multiple of 8
    ssc[t] = pv;
    __syncthreads();
    for (int off = 1; off < 256; off <<= 1) {
        int a = (t >= off) ? ssc[t - off] : 0;
        __syncthreads();
        ssc[t] += a;
        __syncthreads();
    }
    const int myp = ssc[t] - pv;
    pfx[t] = myp;
    const int node = b * 256 + t;
    if (node < N) {
        rowptr[node] = plo + myp;
        rowend[node] = plo + myp + pv;
    }
    __syncthreads();
    const int pcnt = ssc[255];       // <= CAP + 256*7 = 6912 <= PCAP always
    for (int i = t; i < cnt; i += 256) {
        int w = tmp[lo + i];
        int d = w & 255;
        int p = pfx[d] + atomicAdd(&cur[d], 1);
        sadj[p] = w >> 8;
    }
    __syncthreads();
    for (int i = v; i < pv; i++) sadj[myp + i] = N;   // pad -> zero row
    __syncthreads();
    for (int i = t; i < pcnt; i += 256) adj[plo + i] = sadj[i];
}

// ========== aggregation: z[n] = h[n] + sum_m h[m]; rows 8-padded, branch-free ==
// 16 lanes per node, dwordx2 loads: one gather instr = full 128B row per group.
// __launch_bounds__(256,8): cap VGPR at 64 -> 8 waves/EU for latency hiding.
__global__ __launch_bounds__(256, 8) void aggregate_k(
    const bf16* __restrict__ h, const int* __restrict__ rowptr,
    const int* __restrict__ rowend, const int* __restrict__ adj,
    bf16* __restrict__ z, int N)
{
    const int lane16 = threadIdx.x & 15;
    const int n = blockIdx.x * 16 + (threadIdx.x >> 4);
    if (n >= N) return;
    const char* hb_ = (const char*)h;   // row stride 128B
    const int b = rowptr[n], e = rowend[n];

    uint2 u = *(const uint2*)(hb_ + ((size_t)n << 7) + (lane16 << 3));
    float s0 = bl(u.x), s1 = bh(u.x), s2 = bl(u.y), s3 = bh(u.y);

    int m[8];
    if (b < e) {
        #pragma unroll
        for (int k = 0; k < 8; k++) m[k] = adj[b + k];
    }
    for (int i = b; i < e; ) {
        uint2 w[8];
        #pragma unroll
        for (int k = 0; k < 8; k++)
            w[k] = *(const uint2*)(hb_ + (((size_t)(unsigned)m[k]) << 7) + (lane16 << 3));
        const int inext = i + 8;
        if (inext < e) {
            #pragma unroll
            for (int k = 0; k < 8; k++) m[k] = adj[inext + k];
        }
        #pragma unroll
        for (int k = 0; k < 8; k++) {
            s0 += bl(w[k].x); s1 += bh(w[k].x);
            s2 += bl(w[k].y); s3 += bh(w[k].y);
        }
        i = inext;
    }
    uint2 o;
    o.x = pack2(s0, s1);
    o.y = pack2(s2, s3);
    *(uint2*)((char*)z + ((size_t)n << 7) + (lane16 << 3)) = o;
}

// ========== elementwise act: h = relu(y*sc+sh); row N zeroed (pad row) ==========
__global__ __launch_bounds__(256) void ewact_k(
    const bf16* __restrict__ y, const float* __restrict__ sc,
    const float* __restrict__ sh, bf16* __restrict__ h, int N)
{
    const int idx = blockIdx.x * 256 + threadIdx.x;   // one thread = 8 elems
    const int total = (N + 1) * 8;
    if (idx >= total) return;
    short8 v;
    if (idx < N * 8) {
        const int f0 = (idx & 7) * 8;
        v = *(const short8*)(y + (size_t)idx * 8);
        #pragma unroll
        for (int j = 0; j < 8; j++)
            v[j] = f2bs(fmaxf(fmaf(bs2f(v[j]), sc[f0 + j], sh[f0 + j]), 0.f));
    } else {
        #pragma unroll
        for (int j = 0; j < 8; j++) v[j] = 0;
    }
    *(short8*)(h + (size_t)idx * 8) = v;
}

// ---------------- MFMA GEMM (bf16 in/out, f32 acc) ----------------
// C[N x 64] = act(A) @ W + bias.  MODE 0: act = id;  MODE 1: act = relu(A*sc+sh).
// 256 thr = 4 waves; 128 rows/block; per-block stats -> pstat (plain stores; NO
// device fences/atomics -- cross-XCD coherence ops cost ~100us on MI355X).
template<int MODE>
__global__ __launch_bounds__(256) void gemm64_k(
    const bf16* __restrict__ A,
    const float* __restrict__ scin, const float* __restrict__ shin,
    const float* __restrict__ W, const float* __restrict__ bias,
    bf16* __restrict__ out, float* __restrict__ pstat, int nrows)
{
    __shared__ bf16 sWt[64][72];     // transposed W (n-major)
    __shared__ bf16 sC[128][68];     // C tile; 136B rows: 8B-aligned, 2-way bank alias
    __shared__ float sSc[64], sSh[64], sB[64];
    __shared__ float sredS[64][17], sredQ[64][17];
    const int tid = threadIdx.x;

    if (tid < 64) {
        sB[tid] = bias[tid];
        if (MODE == 1) { sSc[tid] = scin[tid]; sSh[tid] = shin[tid]; }
    }
    for (int i = tid; i < 4096; i += 256) {
        int k = i >> 6, n = i & 63;
        sWt[n][k] = f2b(W[i]);
    }
    __syncthreads();

    const int wave = tid >> 6, lane = tid & 63;
    const int quad = lane >> 4, l16 = lane & 15;
    const int row0 = blockIdx.x * 128 + wave * 32;

    short8 a[2][2];
    #pragma unroll
    for (int rt = 0; rt < 2; rt++) {
        int r = row0 + rt * 16 + l16;
        int rr = min(r, nrows - 1);
        const bf16* arow = A + (size_t)rr * 64;
        a[rt][0] = *(const short8*)(arow + quad * 8);
        a[rt][1] = *(const short8*)(arow + 32 + quad * 8);
        if (MODE == 1) {
            #pragma unroll
            for (int j = 0; j < 8; j++) {
                int f0 = quad * 8 + j;
                a[rt][0][j] = f2bs(fmaxf(fmaf(bs2f(a[rt][0][j]), sSc[f0], sSh[f0]), 0.f));
                int f1 = 32 + f0;
                a[rt][1][j] = f2bs(fmaxf(fmaf(bs2f(a[rt][1][j]), sSc[f1], sSh[f1]), 0.f));
            }
        }
    }

    float psS[4], psQ[4];
    #pragma unroll
    for (int t = 0; t < 4; t++) { psS[t] = 0.f; psQ[t] = 0.f; }

    #pragma unroll
    for (int t = 0; t < 4; t++) {
        const int n = t * 16 + l16;
        short8 b0 = *(const short8*)&sWt[n][quad * 8];
        short8 b1 = *(const short8*)&sWt[n][32 + quad * 8];
        const float bn_ = sB[n];
        #pragma unroll
        for (int rt = 0; rt < 2; rt++) {
            f32x4 acc = {0.f, 0.f, 0.f, 0.f};
            acc = __builtin_amdgcn_mfma_f32_16x16x32_bf16(a[rt][0], b0, acc, 0, 0, 0);
            acc = __builtin_amdgcn_mfma_f32_16x16x32_bf16(a[rt][1], b1, acc, 0, 0, 0);
            #pragma unroll
            for (int reg = 0; reg < 4; reg++) {
                const int lr = wave * 32 + rt * 16 + quad * 4 + reg;  // local row
                float v = acc[reg] + bn_;
                sC[lr][n] = f2b(v);
                if (row0 + rt * 16 + quad * 4 + reg < nrows) {
                    psS[t] += v;
                    psQ[t] = fmaf(v, v, psQ[t]);
                }
            }
        }
    }

    #pragma unroll
    for (int t = 0; t < 4; t++) {
        sredS[t * 16 + l16][wave * 4 + quad] = psS[t];
        sredQ[t * 16 + l16][wave * 4 + quad] = psQ[t];
    }
    __syncthreads();

    // coalesced C-tile writeout: 2048 ushort4 chunks (128 rows x 16)
    const int gbase = blockIdx.x * 128;
    #pragma unroll
    for (int it = 0; it < 8; it++) {
        int idx = it * 256 + tid;
        int r = idx >> 4, c4 = idx & 15;
        if (gbase + r < nrows) {
            ushort4 v = *(const ushort4*)&sC[r][c4 * 4];
            *(ushort4*)(out + (size_t)(gbase + r) * 64 + c4 * 4) = v;
        }
    }

    if (tid < 128) {
        const int c = tid & 63;
        const float* p = (tid < 64) ? &sredS[c][0] : &sredQ[c][0];
        float s = 0.f;
        #pragma unroll
        for (int i = 0; i < 16; i++) s += p[i];
        pstat[(size_t)blockIdx.x * 128 + (tid < 64 ? c : 64 + c)] = s;
    }
}

// ---------------- reduce per-block stats -> scale/shift ----------------
__global__ __launch_bounds__(256) void bn_reduce_k(
    const float* __restrict__ pstat, int nblk,
    const float* __restrict__ g, const float* __restrict__ be, float invN,
    float* __restrict__ sc, float* __restrict__ sh)
{
    const int f = blockIdx.x;
    const int t = threadIdx.x;
    float S = 0.f, Q = 0.f;
    for (int b = t; b < nblk; b += 256) {
        S += pstat[(size_t)b * 128 + f];
        Q += pstat[(size_t)b * 128 + 64 + f];
    }
    __shared__ float rs[256], rq[256];
    rs[t] = S; rq[t] = Q;
    __syncthreads();
    for (int off = 128; off > 0; off >>= 1) {
        if (t < off) { rs[t] += rs[t + off]; rq[t] += rq[t + off]; }
        __syncthreads();
    }
    if (t == 0) {
        float m = rs[0] * invN;
        float v = rq[0] * invN - m * m;
        float s = g[f] * rsqrtf(v + BN_EPS);
        sc[f] = s;
        sh[f] = be[f] - m * s;
    }
}

// ---------------- pooled readout; h1 pre-materialized, h2 affine on the fly ------
// 16 groups x 16 lanes; uint2 loads (8B/lane), 4 features per lane.
__global__ __launch_bounds__(256) void pool_readout_k(
    const bf16* __restrict__ xb, const bf16* __restrict__ h1,
    const bf16* __restrict__ y1, const int* __restrict__ batch,
    const float* __restrict__ scB, const float* __restrict__ shB,
    const float* __restrict__ w0, const float* __restrict__ b0,
    const float* __restrict__ w1, const float* __restrict__ b1,
    const float* __restrict__ w2, const float* __restrict__ b2,
    float* __restrict__ out, int Nn)
{
    __shared__ float sB2[2][64];
    __shared__ float p[3][16][64];
    __shared__ float q[3][64];
    const int tid = threadIdx.x;
    if (tid < 64) { sB2[0][tid] = scB[tid]; sB2[1][tid] = shB[tid]; }
    __syncthreads();

    const int g = blockIdx.x;
    int lo = 0, hi = Nn;
    while (lo < hi) { int mid = (lo + hi) >> 1; if (batch[mid] < g) lo = mid + 1; else hi = mid; }
    const int start = lo;
    hi = Nn;
    while (lo < hi) { int mid = (lo + hi) >> 1; if (batch[mid] <= g) lo = mid + 1; else hi = mid; }
    const int end = lo;

    const int l16 = tid & 15, grp = tid >> 4;
    const int f0 = l16 * 4;
    const float scB0 = sB2[0][f0],      shB0 = sB2[1][f0];
    const float scB1 = sB2[0][f0 + 1],  shB1 = sB2[1][f0 + 1];
    const float scB2_ = sB2[0][f0 + 2], shB2_ = sB2[1][f0 + 2];
    const float scB3 = sB2[0][f0 + 3],  shB3 = sB2[1][f0 + 3];

    float a0 = 0.f, a1 = 0.f, a2 = 0.f, a3 = 0.f;
    float h0 = 0.f, h1s = 0.f, h2 = 0.f, h3 = 0.f;
    float c0 = 0.f, c1 = 0.f, c2 = 0.f, c3 = 0.f;
    for (int i = start + grp; i < end; i += 16) {
        const size_t ro = (size_t)i * 16 + l16;
        uint2 ux = ((const uint2*)xb)[ro];
        uint2 u0 = ((const uint2*)h1)[ro];
        uint2 u1 = ((const uint2*)y1)[ro];
        a0 += bl(ux.x); a1 += bh(ux.x); a2 += bl(ux.y); a3 += bh(ux.y);
        h0 += bl(u0.x); h1s += bh(u0.x); h2 += bl(u0.y); h3 += bh(u0.y);
        c0 += fmaxf(fmaf(bl(u1.x), scB0, shB0), 0.f);
        c1 += fmaxf(fmaf(bh(u1.x), scB1, shB1), 0.f);
        c2 += fmaxf(fmaf(bl(u1.y), scB2_, shB2_), 0.f);
        c3 += fmaxf(fmaf(bh(u1.y), scB3, shB3), 0.f);
    }
    p[0][grp][f0] = a0; p[0][grp][f0 + 1] = a1; p[0][grp][f0 + 2] = a2; p[0][grp][f0 + 3] = a3;
    p[1][grp][f0] = h0; p[1][grp][f0 + 1] = h1s; p[1][grp][f0 + 2] = h2; p[1][grp][f0 + 3] = h3;
    p[2][grp][f0] = c0; p[2][grp][f0 + 1] = c1; p[2][grp][f0 + 2] = c2; p[2][grp][f0 + 3] = c3;
    __syncthreads();

    if (tid < 192) {
        const int arr = tid >> 6, f = tid & 63;
        float s = 0.f;
        #pragma unroll
        for (int i = 0; i < 16; i++) s += p[arr][i][f];
        q[arr][f] = s;
    }
    __syncthreads();

    if (tid < 10) {
        const int c = tid;
        float acc = b0[c] + b1[c] + b2[c];
        for (int k = 0; k < 64; k++) {
            acc = fmaf(q[0][k], w0[k * 10 + c], acc);
            acc = fmaf(q[1][k], w1[k * 10 + c], acc);
            acc = fmaf(q[2][k], w2[k * 10 + c], acc);
        }
        out[(size_t)g * 10 + c] = acc;
    }
}

extern "C" void kernel_launch(void* const* d_in, const int* in_sizes, int n_in,
                              void* d_out, int out_size, void* d_ws, size_t ws_size,
                              hipStream_t stream)
{
    const float* x     = (const float*)d_in[0];
    const int*   edge  = (const int*)d_in[1];
    const int*   batch = (const int*)d_in[2];
    const int N = in_sizes[0] / 64;
    const int E = in_sizes[1] / 2;
    const int G = out_size / 10;
    const int* src = edge;
    const int* dst = edge + E;
    const int NB = (N + 255) / 256;

    const float* c_w1[2]  = {(const float*)d_in[3],  (const float*)d_in[11]};
    const float* c_b1[2]  = {(const float*)d_in[4],  (const float*)d_in[12]};
    const float* c_g1[2]  = {(const float*)d_in[5],  (const float*)d_in[13]};
    const float* c_be1[2] = {(const float*)d_in[6],  (const float*)d_in[14]};
    const float* c_w2[2]  = {(const float*)d_in[7],  (const float*)d_in[15]};
    const float* c_b2[2]  = {(const float*)d_in[8],  (const float*)d_in[16]};
    const float* bn_g[2]  = {(const float*)d_in[9],  (const float*)d_in[17]};
    const float* bn_b[2]  = {(const float*)d_in[10], (const float*)d_in[18]};
    const float* lw[3]    = {(const float*)d_in[19], (const float*)d_in[21], (const float*)d_in[23]};
    const float* lb[3]    = {(const float*)d_in[20], (const float*)d_in[22], (const float*)d_in[24]};

    float* out = (float*)d_out;
    const size_t nh1 = (size_t)(N + 1) * 64;   // node buffers have +1 zero pad row
    const int PG = (N + 127) / 128;   // gemm grid

    // workspace layout
    bf16*  zb    = (bf16*)d_ws;                // nh1 (L0 t/y buffer, in-place)
    bf16*  wb    = zb + nh1;                   // nh1 (L1 t/y buffer, in-place)
    bf16*  xb    = wb + nh1;                   // nh1 (x cast, row N = 0)
    bf16*  hb    = xb + nh1;                   // nh1 (h1 = act(y0), row N = 0)
    float* scsh  = (float*)(hb + nh1);         // 8 x 64
    float* pstat = scsh + 512;                 // PG x 128
    int*   rowptr = (int*)(pstat + (size_t)PG * 128);  // N
    int*   rowend = rowptr + N;                // N
    int*   adj    = rowend + N;                // NB*PCAP (8-padded rows)
    int*   tmp    = adj + (size_t)NB * PCAP;   // NB*CAP
    int*   bcur   = tmp + (size_t)NB * CAP;    // NB

    float* sc0 = scsh;       float* sh0 = scsh + 64;
    float* scA = scsh + 128; float* shA = scsh + 192;
    float* sc2 = scsh + 256; float* sh2 = scsh + 320;
    float* scB = scsh + 384; float* shB = scsh + 448;

    const float invN = 1.0f / (float)N;
    const int binGrid  = (E + CHUNK - 1) / CHUNK;
    const int aggGrid  = (N + 15) / 16;
    const int n4       = N * 16;               // cast region in 4-elem chunks
    const int total4   = (N + 1) * 16;         // + pad row
    const int ewGrid   = (total4 + 255) / 256;
    const int actGrid  = ((N + 1) * 8 + 255) / 256;

    // ---- init+cast, CSR build (fixed-stride buckets, 8-padded rows) ----
    initcast_k<<<ewGrid, 256, 0, stream>>>(x, xb, n4, total4, bcur, NB);
    binscatter_k<<<binGrid, 256, 0, stream>>>(src, dst, bcur, tmp, E, NB);
    csr_k<<<NB, 256, 0, stream>>>(bcur, tmp, rowptr, rowend, adj, N);

    // ---- layer 0 ----
    aggregate_k<<<aggGrid, 256, 0, stream>>>(xb, rowptr, rowend, adj, zb, N);
    gemm64_k<0><<<PG, 256, 0, stream>>>(zb, nullptr, nullptr,
                                        c_w1[0], c_b1[0], zb, pstat, N);
    bn_reduce_k<<<64, 256, 0, stream>>>(pstat, PG, c_g1[0], c_be1[0], invN, sc0, sh0);
    gemm64_k<1><<<PG, 256, 0, stream>>>(zb, sc0, sh0,
                                        c_w2[0], c_b2[0], zb, pstat, N);
    bn_reduce_k<<<64, 256, 0, stream>>>(pstat, PG, bn_g[0], bn_b[0], invN, scA, shA);

    // ---- h1 = relu(affine(y0)) materialized once (pad row zeroed) ----
    ewact_k<<<actGrid, 256, 0, stream>>>(zb, scA, shA, hb, N);

    // ---- layer 1 ----
    aggregate_k<<<aggGrid, 256, 0, stream>>>(hb, rowptr, rowend, adj, wb, N);
    gemm64_k<0><<<PG, 256, 0, stream>>>(wb, nullptr, nullptr,
                                        c_w1[1], c_b1[1], wb, pstat, N);
    bn_reduce_k<<<64, 256, 0, stream>>>(pstat, PG, c_g1[1], c_be1[1], invN, sc2, sh2);
    gemm64_k<1><<<PG, 256, 0, stream>>>(wb, sc2, sh2,
                                        c_w2[1], c_b2[1], wb, pstat, N);
    bn_reduce_k<<<64, 256, 0, stream>>>(pstat, PG, bn_g[1], bn_b[1], invN, scB, shB);

    // ---- pooled readout (h2 affine+relu fused) ----
    pool_readout_k<<<G, 256, 0, stream>>>(xb, hb, wb, batch,
                                          scB, shB,
                                          lw[0], lb[0], lw[1], lb[1], lw[2], lb[2],
                                          out, N);
}